// Round 1
// baseline (161.218 us; speedup 1.0000x reference)
//
#include <hip/hip_runtime.h>
#include <math.h>

#define BB 32
#define NN 1024

// ---------------------------------------------------------------------------
// K1: partial column sums of y.  grid (B, 16), block 256.
// thread t owns columns 4t..4t+3 (float4 coalesced loads), rows [r*64, r*64+64)
// P1 layout: [r][b][N]
// ---------------------------------------------------------------------------
__global__ void k1_colsum(const float* __restrict__ y, float* __restrict__ P1) {
    const int b = blockIdx.x, r = blockIdx.y;
    const int j0 = threadIdx.x * 4;
    const float* base = y + (size_t)b * NN * NN;
    const int i0 = r * 64;
    float4 acc = make_float4(0.f, 0.f, 0.f, 0.f);
#pragma unroll 8
    for (int i = 0; i < 64; ++i) {
        float4 v = *(const float4*)(base + (size_t)(i0 + i) * NN + j0);
        acc.x += v.x; acc.y += v.y; acc.z += v.z; acc.w += v.w;
    }
    *(float4*)(P1 + ((size_t)r * BB + b) * NN + j0) = acc;
}

// ---------------------------------------------------------------------------
// K2: deg -> dinv, dfill.  B*N threads.
// deg[b,j] = sum_r P1 + fill (fill = 1 if y[b,j,j]==0)
// dinv = deg>0 ? rsqrt(deg) : 0 ; dfill = dinv*fill
// ---------------------------------------------------------------------------
__global__ void k2_dinv(const float* __restrict__ y, const float* __restrict__ P1,
                        float* __restrict__ dinv, float* __restrict__ dfill) {
    const int idx = blockIdx.x * 256 + threadIdx.x;
    const int b = idx >> 10, j = idx & 1023;
    float s = 0.f;
#pragma unroll
    for (int r = 0; r < 16; ++r) s += P1[((size_t)r * BB + b) * NN + j];
    const float dia = y[((size_t)b * NN + j) * NN + j];
    const float fill = (dia == 0.0f) ? 1.0f : 0.0f;
    const float deg = s + fill;
    const float dv = (deg > 0.0f) ? (1.0f / sqrtf(deg)) : 0.0f;
    dinv[idx] = dv;
    dfill[idx] = dv * fill;
}

// ---------------------------------------------------------------------------
// K3a: weighted partial column sums  S1p = sum_i dinv[i]*y[i,j]
// same shape as K1.  P2 layout: [r][b][N]
// ---------------------------------------------------------------------------
__global__ void k3a_wcolsum(const float* __restrict__ y, const float* __restrict__ dinv,
                            float* __restrict__ P2) {
    const int b = blockIdx.x, r = blockIdx.y;
    const int j0 = threadIdx.x * 4;
    const float* base = y + (size_t)b * NN * NN;
    const float* dv = dinv + b * NN;
    const int i0 = r * 64;
    float4 acc = make_float4(0.f, 0.f, 0.f, 0.f);
#pragma unroll 8
    for (int i = 0; i < 64; ++i) {
        const float di = dv[i0 + i];  // wave-uniform
        float4 v = *(const float4*)(base + (size_t)(i0 + i) * NN + j0);
        acc.x += v.x * di; acc.y += v.y * di; acc.z += v.z * di; acc.w += v.w * di;
    }
    *(float4*)(P2 + ((size_t)r * BB + b) * NN + j0) = acc;
}

// ---------------------------------------------------------------------------
// K3b: finalize colsum1, compute hW2[b,j,0:16].  B*N threads.
// s = dinv[j]*(sum_r P2 + dfill[j]);  x1[f]=relu(s*W1[f]+b1[f]);
// hW2[g] = sum_f x1[f]*W2[f,g]
// ---------------------------------------------------------------------------
__global__ void k3b_hw2(const float* __restrict__ P2, const float* __restrict__ dinv,
                        const float* __restrict__ dfill,
                        const float* __restrict__ W1, const float* __restrict__ b1,
                        const float* __restrict__ W2, float* __restrict__ hW2) {
    const int idx = blockIdx.x * 256 + threadIdx.x;
    const int b = idx >> 10;
    const int j = idx & 1023;
    float s = 0.f;
#pragma unroll
    for (int r = 0; r < 16; ++r) s += P2[((size_t)r * BB + b) * NN + j];
    s += dfill[idx];
    const float cs = dinv[idx] * s;

    float h[16];
#pragma unroll
    for (int g = 0; g < 16; ++g) h[g] = 0.f;
#pragma unroll 4
    for (int f = 0; f < 64; ++f) {
        float x1 = cs * W1[f] + b1[f];
        x1 = x1 > 0.f ? x1 : 0.f;
        const float4* w2r = (const float4*)(W2 + f * 16);
        float4 w0 = w2r[0], w1v = w2r[1], w2v = w2r[2], w3 = w2r[3];
        h[0] += x1 * w0.x;  h[1] += x1 * w0.y;  h[2] += x1 * w0.z;  h[3] += x1 * w0.w;
        h[4] += x1 * w1v.x; h[5] += x1 * w1v.y; h[6] += x1 * w1v.z; h[7] += x1 * w1v.w;
        h[8] += x1 * w2v.x; h[9] += x1 * w2v.y; h[10] += x1 * w2v.z; h[11] += x1 * w2v.w;
        h[12] += x1 * w3.x; h[13] += x1 * w3.y; h[14] += x1 * w3.z; h[15] += x1 * w3.w;
    }
    float* o = hW2 + (size_t)idx * 16;
    *(float4*)(o + 0)  = make_float4(h[0], h[1], h[2], h[3]);
    *(float4*)(o + 4)  = make_float4(h[4], h[5], h[6], h[7]);
    *(float4*)(o + 8)  = make_float4(h[8], h[9], h[10], h[11]);
    *(float4*)(o + 12) = make_float4(h[12], h[13], h[14], h[15]);
}

// ---------------------------------------------------------------------------
// K4: rank-16 weighted column reduction partials.
// grid (B, RS2), block 256; thread owns cols 4t..4t+3, all 16 g (64 f32 acc).
// P3 layout: [r][b][16][N]  (coalesced float4 stores per g)
// ---------------------------------------------------------------------------
__global__ void k4_agg(const float* __restrict__ y, const float* __restrict__ dinv,
                       const float* __restrict__ hW2, float* __restrict__ P3,
                       int rowsPerBlk) {
    const int b = blockIdx.x, r = blockIdx.y;
    const int j0 = threadIdx.x * 4;
    const float* base = y + (size_t)b * NN * NN;
    const float* dv = dinv + b * NN;
    const float* hb = hW2 + (size_t)b * NN * 16;

    float4 acc[16];
#pragma unroll
    for (int g = 0; g < 16; ++g) acc[g] = make_float4(0.f, 0.f, 0.f, 0.f);

    const int i0 = r * rowsPerBlk;
    float4 vnext = *(const float4*)(base + (size_t)i0 * NN + j0);
    for (int i = 0; i < rowsPerBlk; ++i) {
        float4 v = vnext;
        if (i + 1 < rowsPerBlk)
            vnext = *(const float4*)(base + (size_t)(i0 + i + 1) * NN + j0);
        const float di = dv[i0 + i];                       // wave-uniform
        const float4* hr = (const float4*)(hb + (size_t)(i0 + i) * 16);  // wave-uniform
        float4 h0 = hr[0], h1 = hr[1], h2 = hr[2], h3 = hr[3];
        float4 a;
        a.x = v.x * di; a.y = v.y * di; a.z = v.z * di; a.w = v.w * di;
#define STEP(G, HS) acc[G].x += a.x * (HS); acc[G].y += a.y * (HS); \
                    acc[G].z += a.z * (HS); acc[G].w += a.w * (HS);
        STEP(0, h0.x)  STEP(1, h0.y)  STEP(2, h0.z)  STEP(3, h0.w)
        STEP(4, h1.x)  STEP(5, h1.y)  STEP(6, h1.z)  STEP(7, h1.w)
        STEP(8, h2.x)  STEP(9, h2.y)  STEP(10, h2.z) STEP(11, h2.w)
        STEP(12, h3.x) STEP(13, h3.y) STEP(14, h3.z) STEP(15, h3.w)
#undef STEP
    }
#pragma unroll
    for (int g = 0; g < 16; ++g)
        *(float4*)(P3 + (((size_t)r * BB + b) * 16 + g) * NN + j0) = acc[g];
}

// ---------------------------------------------------------------------------
// K4r: reduce P3, finalize out2, rowmax.  B*N threads.
// out2[j,g] = dinv[j]*(S3 + dfill[j]*hW2[j,g]) + b2[g];  rowmax = max_g
// ---------------------------------------------------------------------------
__global__ void k4r_max(const float* __restrict__ P3, const float* __restrict__ dinv,
                        const float* __restrict__ dfill, const float* __restrict__ hW2,
                        const float* __restrict__ b2, float* __restrict__ rowmax,
                        int RS2) {
    const int idx = blockIdx.x * 256 + threadIdx.x;
    const int b = idx >> 10, j = idx & 1023;
    const float dv = dinv[idx], df = dfill[idx];
    const float* hp = hW2 + (size_t)idx * 16;
    float m = -3.4e38f;
#pragma unroll
    for (int g = 0; g < 16; ++g) {
        float s = 0.f;
        for (int r = 0; r < RS2; ++r)
            s += P3[(((size_t)r * BB + b) * 16 + g) * NN + j];
        const float o = dv * (s + df * hp[g]) + b2[g];
        m = fmaxf(m, o);
    }
    rowmax[idx] = m;
}

// ---------------------------------------------------------------------------
// K5: head — (B,N) @ Wm1(N,32) + bm1 -> @ Wm2(32,16) + bm2.  1 block / batch.
// ---------------------------------------------------------------------------
__global__ __launch_bounds__(1024) void k5_head(const float* __restrict__ rowmax,
                                                const float* __restrict__ Wm1,
                                                const float* __restrict__ bm1,
                                                const float* __restrict__ Wm2,
                                                const float* __restrict__ bm2,
                                                float* __restrict__ out) {
    __shared__ float sm[NN];
    __shared__ float p[32 * 32];
    __shared__ float z[32];
    const int b = blockIdx.x, t = threadIdx.x;
    sm[t] = rowmax[(size_t)b * NN + t];
    __syncthreads();
    const int k = t & 31, c = t >> 5;   // c: 0..31 chunks of 32 rows
    float acc = 0.f;
#pragma unroll 8
    for (int q = 0; q < 32; ++q) {
        const int j = c * 32 + q;
        acc += sm[j] * Wm1[j * 32 + k];
    }
    p[c * 32 + k] = acc;
    __syncthreads();
    if (t < 32) {
        float s = 0.f;
#pragma unroll
        for (int c2 = 0; c2 < 32; ++c2) s += p[c2 * 32 + t];
        z[t] = s + bm1[t];
    }
    __syncthreads();
    if (t < 16) {
        float s = 0.f;
#pragma unroll
        for (int k2 = 0; k2 < 32; ++k2) s += z[k2] * Wm2[k2 * 16 + t];
        out[b * 16 + t] = s + bm2[t];
    }
}

// ---------------------------------------------------------------------------
extern "C" void kernel_launch(void* const* d_in, const int* in_sizes, int n_in,
                              void* d_out, int out_size, void* d_ws, size_t ws_size,
                              hipStream_t stream) {
    const float* y   = (const float*)d_in[0];
    const float* W1  = (const float*)d_in[1];
    const float* b1  = (const float*)d_in[2];
    const float* W2  = (const float*)d_in[3];
    const float* b2  = (const float*)d_in[4];
    const float* Wm1 = (const float*)d_in[5];
    const float* bm1 = (const float*)d_in[6];
    const float* Wm2 = (const float*)d_in[7];
    const float* bm2 = (const float*)d_in[8];
    float* ws = (float*)d_ws;

    size_t off = 0;
    float* P1     = ws + off; off += (size_t)16 * BB * NN;       // 2 MB
    float* P2     = ws + off; off += (size_t)16 * BB * NN;       // 2 MB
    float* dinv   = ws + off; off += (size_t)BB * NN;
    float* dfill  = ws + off; off += (size_t)BB * NN;
    float* hW2    = ws + off; off += (size_t)BB * NN * 16;       // 2 MB
    float* rowmax = ws + off; off += (size_t)BB * NN;
    float* P3     = ws + off;

    const size_t remainFloats = ws_size / 4 - off;
    int RS2 = 16;
    while (RS2 > 1 && (size_t)RS2 * BB * 16 * NN > remainFloats) RS2 >>= 1;
    const int rows2 = NN / RS2;

    k1_colsum<<<dim3(BB, 16), 256, 0, stream>>>(y, P1);
    k2_dinv<<<dim3(BB * NN / 256), 256, 0, stream>>>(y, P1, dinv, dfill);
    k3a_wcolsum<<<dim3(BB, 16), 256, 0, stream>>>(y, dinv, P2);
    k3b_hw2<<<dim3(BB * NN / 256), 256, 0, stream>>>(P2, dinv, dfill, W1, b1, W2, hW2);
    k4_agg<<<dim3(BB, RS2), 256, 0, stream>>>(y, dinv, hW2, P3, rows2);
    k4r_max<<<dim3(BB * NN / 256), 256, 0, stream>>>(P3, dinv, dfill, hW2, b2, rowmax, RS2);
    k5_head<<<dim3(BB), 1024, 0, stream>>>(rowmax, Wm1, bm1, Wm2, bm2, (float*)d_out);
}

// Round 2
// 77.718 us; speedup vs baseline: 2.0744x; 2.0744x over previous
//
#include <hip/hip_runtime.h>
#include <math.h>

#define BB 32
#define NN 1024

// ===========================================================================
// Column-split structure for all y-sweeps:
//   grid (B=32, 16) = 512 blocks, block 256 = 16 col-threads (ct, 4 cols each
//   as float4) x 16 row-groups (rg, 64 rows each). Cross-rowgroup reduction
//   happens in LDS; every pass finalizes in-block (no global partials).
// ===========================================================================

// ---------------------------------------------------------------------------
// kA (pass 1): deg = colsum(y) + diag fill -> dinv, dfill
// ---------------------------------------------------------------------------
__global__ __launch_bounds__(256) void kA(const float* __restrict__ y,
                                          float* __restrict__ dinv,
                                          float* __restrict__ dfill) {
    __shared__ float red[16 * 68];      // [rg][68] pad: 2-way reads (free)
    const int b = blockIdx.x, by = blockIdx.y;
    const int t = threadIdx.x, ct = t & 15, rg = t >> 4;
    const int j0 = by * 64 + ct * 4;
    const float* base = y + (size_t)b * NN * NN + (size_t)(rg * 64) * NN + j0;
    float4 acc = make_float4(0.f, 0.f, 0.f, 0.f);
#pragma unroll 8
    for (int i = 0; i < 64; ++i) {
        float4 v = *(const float4*)(base + (size_t)i * NN);
        acc.x += v.x; acc.y += v.y; acc.z += v.z; acc.w += v.w;
    }
    *(float4*)&red[rg * 68 + ct * 4] = acc;
    __syncthreads();
    if (t < 64) {
        float s = 0.f;
#pragma unroll
        for (int r = 0; r < 16; ++r) s += red[r * 68 + t];
        const int j = by * 64 + t;
        const float dia = y[((size_t)b * NN + j) * NN + j];
        const float fill = (dia == 0.0f) ? 1.0f : 0.0f;
        const float deg = s + fill;
        const float dv = (deg > 0.0f) ? (1.0f / sqrtf(deg)) : 0.0f;
        dinv[b * NN + j] = dv;
        dfill[b * NN + j] = dv * fill;
    }
}

// ---------------------------------------------------------------------------
// kB (pass 2): cs[j] = dinv[j]*(sum_i dinv[i]*y[i,j] + dfill[j]);
//              hW2[j,g] = sum_f relu(cs*W1[f]+b1[f]) * W2[f,g]
// ---------------------------------------------------------------------------
__global__ __launch_bounds__(256) void kB(const float* __restrict__ y,
                                          const float* __restrict__ dinv,
                                          const float* __restrict__ dfill,
                                          const float* __restrict__ W1,
                                          const float* __restrict__ b1,
                                          const float* __restrict__ W2,
                                          float* __restrict__ hW2) {
    __shared__ float red[16 * 68];
    __shared__ float csb[64];
    const int b = blockIdx.x, by = blockIdx.y;
    const int t = threadIdx.x, ct = t & 15, rg = t >> 4;
    const int j0 = by * 64 + ct * 4;
    const float* base = y + (size_t)b * NN * NN + (size_t)(rg * 64) * NN + j0;
    const float* dvp = dinv + b * NN + rg * 64;
    float4 acc = make_float4(0.f, 0.f, 0.f, 0.f);
#pragma unroll 8
    for (int i = 0; i < 64; ++i) {
        const float di = dvp[i];
        float4 v = *(const float4*)(base + (size_t)i * NN);
        acc.x += v.x * di; acc.y += v.y * di; acc.z += v.z * di; acc.w += v.w * di;
    }
    *(float4*)&red[rg * 68 + ct * 4] = acc;
    __syncthreads();
    if (t < 64) {
        float s = 0.f;
#pragma unroll
        for (int r = 0; r < 16; ++r) s += red[r * 68 + t];
        const int idx = b * NN + by * 64 + t;
        csb[t] = dinv[idx] * (s + dfill[idx]);
    }
    __syncthreads();
    // 256 threads = 64 cols x 4 g-quarters
    const int q = t >> 2, gq = t & 3;
    const float cs = csb[q];
    float4 h = make_float4(0.f, 0.f, 0.f, 0.f);
#pragma unroll
    for (int f = 0; f < 64; ++f) {
        float x1 = fmaf(cs, W1[f], b1[f]);
        x1 = x1 > 0.f ? x1 : 0.f;
        float4 w = *(const float4*)(W2 + f * 16 + gq * 4);
        h.x += x1 * w.x; h.y += x1 * w.y; h.z += x1 * w.z; h.w += x1 * w.w;
    }
    const int j = by * 64 + q;
    *(float4*)(hW2 + ((size_t)(b * NN + j)) * 16 + gq * 4) = h;  // 16B/lane coalesced
}

// ---------------------------------------------------------------------------
// kC (pass 3): out2[j,g] = dinv[j]*(sum_i dinv[i]*y[i,j]*hW2[i,g]
//                                   + dfill[j]*hW2[j,g]) + b2[g];
//              rowmax[j] = max_g out2[j,g].   No global partials.
// LDS reduce layout: float4 slot (rg*256 + ct*16 + p), p = (g+ct+rg)&15
//   -> b128 writes evenly spread over bank-quads, reads 2-way (free).
// ---------------------------------------------------------------------------
__global__ __launch_bounds__(256) void kC(const float* __restrict__ y,
                                          const float* __restrict__ dinv,
                                          const float* __restrict__ dfill,
                                          const float* __restrict__ hW2,
                                          const float* __restrict__ b2,
                                          float* __restrict__ rowmax) {
    __shared__ float red[16 * 16 * 16 * 4];   // 64 KB
    const int b = blockIdx.x, by = blockIdx.y;
    const int t = threadIdx.x, ct = t & 15, rg = t >> 4;
    const int j0 = by * 64 + ct * 4;
    const float* base = y + (size_t)b * NN * NN + (size_t)(rg * 64) * NN + j0;
    const float* dvp = dinv + b * NN + rg * 64;
    const float* hp = hW2 + ((size_t)(b * NN + rg * 64)) * 16;

    float4 acc[16];
#pragma unroll
    for (int g = 0; g < 16; ++g) acc[g] = make_float4(0.f, 0.f, 0.f, 0.f);

#pragma unroll 4
    for (int i = 0; i < 64; ++i) {
        float4 v = *(const float4*)(base + (size_t)i * NN);
        const float di = dvp[i];
        const float4* hr = (const float4*)(hp + (size_t)i * 16);
        float4 h0 = hr[0], h1 = hr[1], h2 = hr[2], h3 = hr[3];
        float4 a;
        a.x = v.x * di; a.y = v.y * di; a.z = v.z * di; a.w = v.w * di;
#define STEP(G, HS) acc[G].x += a.x * (HS); acc[G].y += a.y * (HS); \
                    acc[G].z += a.z * (HS); acc[G].w += a.w * (HS);
        STEP(0, h0.x)  STEP(1, h0.y)  STEP(2, h0.z)  STEP(3, h0.w)
        STEP(4, h1.x)  STEP(5, h1.y)  STEP(6, h1.z)  STEP(7, h1.w)
        STEP(8, h2.x)  STEP(9, h2.y)  STEP(10, h2.z) STEP(11, h2.w)
        STEP(12, h3.x) STEP(13, h3.y) STEP(14, h3.z) STEP(15, h3.w)
#undef STEP
    }
#pragma unroll
    for (int g = 0; g < 16; ++g) {
        const int p = (g + ct + rg) & 15;
        *(float4*)&red[(rg * 256 + ct * 16 + p) * 4] = acc[g];
    }
    __syncthreads();
    // reduce: thread t owns col q = t>>2 (j = by*64+q), g-quarter gq = t&3
    const int q = t >> 2, gq = t & 3;
    const int cti = q >> 2, kk = q & 3;
    const int j = by * 64 + q;
    const int idx = b * NN + j;
    const float dv = dinv[idx], df = dfill[idx];
    const float* hj = hW2 + (size_t)idx * 16;
    float m = -3.4e38f;
#pragma unroll
    for (int e = 0; e < 4; ++e) {
        const int g = gq * 4 + e;
        float s = 0.f;
#pragma unroll
        for (int r = 0; r < 16; ++r) {
            const int p = (g + cti + r) & 15;
            s += red[(r * 256 + cti * 16 + p) * 4 + kk];
        }
        const float ov = dv * (s + df * hj[g]) + b2[g];
        m = fmaxf(m, ov);
    }
    m = fmaxf(m, __shfl_xor(m, 1));
    m = fmaxf(m, __shfl_xor(m, 2));
    if ((t & 3) == 0) rowmax[idx] = m;
}

// ---------------------------------------------------------------------------
// k5: head — (B,N) @ Wm1(N,32) + bm1 -> @ Wm2(32,16) + bm2.  1 block / batch.
// ---------------------------------------------------------------------------
__global__ __launch_bounds__(1024) void k5_head(const float* __restrict__ rowmax,
                                                const float* __restrict__ Wm1,
                                                const float* __restrict__ bm1,
                                                const float* __restrict__ Wm2,
                                                const float* __restrict__ bm2,
                                                float* __restrict__ out) {
    __shared__ float sm[NN];
    __shared__ float p[32 * 32];
    __shared__ float z[32];
    const int b = blockIdx.x, t = threadIdx.x;
    sm[t] = rowmax[(size_t)b * NN + t];
    __syncthreads();
    const int k = t & 31, c = t >> 5;
    float acc = 0.f;
#pragma unroll 8
    for (int qq = 0; qq < 32; ++qq) {
        const int j = c * 32 + qq;
        acc += sm[j] * Wm1[j * 32 + k];
    }
    p[c * 32 + k] = acc;
    __syncthreads();
    if (t < 32) {
        float s = 0.f;
#pragma unroll
        for (int c2 = 0; c2 < 32; ++c2) s += p[c2 * 32 + t];
        z[t] = s + bm1[t];
    }
    __syncthreads();
    if (t < 16) {
        float s = 0.f;
#pragma unroll
        for (int k2 = 0; k2 < 32; ++k2) s += z[k2] * Wm2[k2 * 16 + t];
        out[b * 16 + t] = s + bm2[t];
    }
}

// ---------------------------------------------------------------------------
extern "C" void kernel_launch(void* const* d_in, const int* in_sizes, int n_in,
                              void* d_out, int out_size, void* d_ws, size_t ws_size,
                              hipStream_t stream) {
    const float* y   = (const float*)d_in[0];
    const float* W1  = (const float*)d_in[1];
    const float* b1  = (const float*)d_in[2];
    const float* W2  = (const float*)d_in[3];
    const float* b2  = (const float*)d_in[4];
    const float* Wm1 = (const float*)d_in[5];
    const float* bm1 = (const float*)d_in[6];
    const float* Wm2 = (const float*)d_in[7];
    const float* bm2 = (const float*)d_in[8];
    float* ws = (float*)d_ws;

    size_t off = 0;
    float* dinv   = ws + off; off += (size_t)BB * NN;
    float* dfill  = ws + off; off += (size_t)BB * NN;
    float* rowmax = ws + off; off += (size_t)BB * NN;
    float* hW2    = ws + off; off += (size_t)BB * NN * 16;   // 2 MB

    kA<<<dim3(BB, 16), 256, 0, stream>>>(y, dinv, dfill);
    kB<<<dim3(BB, 16), 256, 0, stream>>>(y, dinv, dfill, W1, b1, W2, hW2);
    kC<<<dim3(BB, 16), 256, 0, stream>>>(y, dinv, dfill, hW2, b2, rowmax);
    k5_head<<<dim3(BB), 1024, 0, stream>>>(rowmax, Wm1, bm1, Wm2, bm2, (float*)d_out);
}